// Round 1
// baseline (5946.197 us; speedup 1.0000x reference)
//
#include <hip/hip_runtime.h>
#include <math.h>

// Problem constants (match the reference)
constexpr int B_   = 8;
constexpr int S_   = 512;
constexpr int D_   = 1024;
constexpr int H_   = 16;
constexpr int NL_  = 6;
constexpr int DFF_ = 512;
constexpr int DK_  = 64;    // D/H
constexpr int M_   = B_ * S_;   // 4096 rows
constexpr float EPS_   = 1e-6f;
constexpr float SCALE_ = 0.125f; // 1/sqrt(64)

// ---------------------------------------------------------------------------
// Generic fp32 GEMM: C[M,N] = A[M,K] @ W[K,N] + bias[N]
// 64x64 tile, BK=16, 256 threads, 4x4 microtile per thread.
// EPI: 0 = plain, 1 = scatter output to [B,H,S,DK] (QKV proj), 2 = ReLU
// ---------------------------------------------------------------------------
template <int EPI>
__global__ __launch_bounds__(256) void gemm64(
    const float* __restrict__ A, const float* __restrict__ W,
    const float* __restrict__ bias, float* __restrict__ C,
    int M, int N, int K)
{
    __shared__ float sA[16][64];
    __shared__ float sB[16][64];

    const int tid  = threadIdx.x;
    const int col0 = blockIdx.x * 64;
    const int row0 = blockIdx.y * 64;
    const int tx = tid & 15;        // 16 thread cols * 4 = 64 cols
    const int ty = tid >> 4;        // 16 thread rows * 4 = 64 rows
    const int lm  = tid >> 2;       // A-load: row within tile
    const int lk4 = (tid & 3) << 2; // A-load: k quad
    const int lkk = tid >> 4;       // B-load: k within tile
    const int ln4 = (tid & 15) << 2;// B-load: col quad

    float acc[4][4] = {};

    const float* Arow = A + (size_t)(row0 + lm) * K + lk4;
    const float* Wrow = W + (size_t)lkk * N + col0 + ln4;

    for (int k0 = 0; k0 < K; k0 += 16) {
        const float4 a4 = *(const float4*)(Arow + k0);
        const float4 b4 = *(const float4*)(Wrow + (size_t)k0 * N);
        sA[lk4 + 0][lm] = a4.x;
        sA[lk4 + 1][lm] = a4.y;
        sA[lk4 + 2][lm] = a4.z;
        sA[lk4 + 3][lm] = a4.w;
        *(float4*)&sB[lkk][ln4] = b4;
        __syncthreads();
#pragma unroll
        for (int kk = 0; kk < 16; ++kk) {
            float a0 = sA[kk][ty * 4 + 0];
            float a1 = sA[kk][ty * 4 + 1];
            float a2 = sA[kk][ty * 4 + 2];
            float a3 = sA[kk][ty * 4 + 3];
            float b0 = sB[kk][tx * 4 + 0];
            float b1 = sB[kk][tx * 4 + 1];
            float b2 = sB[kk][tx * 4 + 2];
            float b3 = sB[kk][tx * 4 + 3];
            acc[0][0] += a0 * b0; acc[0][1] += a0 * b1; acc[0][2] += a0 * b2; acc[0][3] += a0 * b3;
            acc[1][0] += a1 * b0; acc[1][1] += a1 * b1; acc[1][2] += a1 * b2; acc[1][3] += a1 * b3;
            acc[2][0] += a2 * b0; acc[2][1] += a2 * b1; acc[2][2] += a2 * b2; acc[2][3] += a2 * b3;
            acc[3][0] += a3 * b0; acc[3][1] += a3 * b1; acc[3][2] += a3 * b2; acc[3][3] += a3 * b3;
        }
        __syncthreads();
    }

#pragma unroll
    for (int i = 0; i < 4; ++i) {
        const int m = row0 + ty * 4 + i;
#pragma unroll
        for (int j = 0; j < 4; ++j) {
            const int n = col0 + tx * 4 + j;
            float v = acc[i][j] + bias[n];
            if (EPI == 2) v = fmaxf(v, 0.0f);
            if (EPI == 1) {
                // scatter to [B,H,S,DK]: m = b*S+s, n = h*DK+dk
                const int b  = m >> 9;       // /S
                const int s  = m & 511;      // %S
                const int h  = n >> 6;       // /DK
                const int dk = n & 63;       // %DK
                C[(((size_t)(b * H_ + h)) * S_ + s) * DK_ + dk] = v;
            } else {
                C[(size_t)m * N + n] = v;
            }
        }
    }
}

// ---------------------------------------------------------------------------
// QK^T: per (b,h), scores[q,k] = scale * sum_d Q[q,d]*K[k,d]
// Q,K in [B,H,S,DK]. Writes directly into the d_out attention slice.
// Grid: (S/64, S/64, B*H)
// ---------------------------------------------------------------------------
__global__ __launch_bounds__(256) void qkt_kernel(
    const float* __restrict__ Q, const float* __restrict__ Km,
    float* __restrict__ attnL)   // attnL = outAttn + layer*H*S*S
{
    const int bh = blockIdx.z;       // 0..127
    const int kt = blockIdx.x;       // k tile
    const int qt = blockIdx.y;       // q tile
    const int b  = bh >> 4;
    const int h  = bh & 15;

    const float* Qb = Q  + (size_t)bh * S_ * DK_;
    const float* Kb = Km + (size_t)bh * S_ * DK_;
    float* out = attnL + ((size_t)b * (NL_ * H_) + h) * (size_t)(S_ * S_);

    __shared__ float sQ[16][64];
    __shared__ float sK[16][64];

    const int tid = threadIdx.x;
    const int tx = tid & 15, ty = tid >> 4;
    const int lm  = tid >> 2;
    const int lk4 = (tid & 3) << 2;

    float acc[4][4] = {};

    for (int k0 = 0; k0 < DK_; k0 += 16) {
        const float4 q4 = *(const float4*)(Qb + (size_t)(qt * 64 + lm) * DK_ + k0 + lk4);
        const float4 k4 = *(const float4*)(Kb + (size_t)(kt * 64 + lm) * DK_ + k0 + lk4);
        sQ[lk4 + 0][lm] = q4.x; sQ[lk4 + 1][lm] = q4.y; sQ[lk4 + 2][lm] = q4.z; sQ[lk4 + 3][lm] = q4.w;
        sK[lk4 + 0][lm] = k4.x; sK[lk4 + 1][lm] = k4.y; sK[lk4 + 2][lm] = k4.z; sK[lk4 + 3][lm] = k4.w;
        __syncthreads();
#pragma unroll
        for (int kk = 0; kk < 16; ++kk) {
            float a0 = sQ[kk][ty * 4 + 0];
            float a1 = sQ[kk][ty * 4 + 1];
            float a2 = sQ[kk][ty * 4 + 2];
            float a3 = sQ[kk][ty * 4 + 3];
            float b0 = sK[kk][tx * 4 + 0];
            float b1 = sK[kk][tx * 4 + 1];
            float b2 = sK[kk][tx * 4 + 2];
            float b3 = sK[kk][tx * 4 + 3];
            acc[0][0] += a0 * b0; acc[0][1] += a0 * b1; acc[0][2] += a0 * b2; acc[0][3] += a0 * b3;
            acc[1][0] += a1 * b0; acc[1][1] += a1 * b1; acc[1][2] += a1 * b2; acc[1][3] += a1 * b3;
            acc[2][0] += a2 * b0; acc[2][1] += a2 * b1; acc[2][2] += a2 * b2; acc[2][3] += a2 * b3;
            acc[3][0] += a3 * b0; acc[3][1] += a3 * b1; acc[3][2] += a3 * b2; acc[3][3] += a3 * b3;
        }
        __syncthreads();
    }

#pragma unroll
    for (int i = 0; i < 4; ++i) {
        const int qr = qt * 64 + ty * 4 + i;
#pragma unroll
        for (int j = 0; j < 4; ++j) {
            const int kc = kt * 64 + tx * 4 + j;
            out[(size_t)qr * S_ + kc] = acc[i][j] * SCALE_;
        }
    }
}

// ---------------------------------------------------------------------------
// In-place row softmax over 512-element rows of the attn slice.
// Grid: B*H*S blocks of 256 threads (2 elements/thread).
// ---------------------------------------------------------------------------
__global__ __launch_bounds__(256) void softmax_kernel(float* __restrict__ attnL)
{
    const int idx  = blockIdx.x;       // bh*S + q
    const int bh   = idx >> 9;
    const int qrow = idx & 511;
    const int b = bh >> 4, h = bh & 15;
    float* row = attnL + ((size_t)b * (NL_ * H_) + h) * (size_t)(S_ * S_) + (size_t)qrow * S_;

    const int tid = threadIdx.x;
    float v0 = row[tid];
    float v1 = row[tid + 256];

    __shared__ float red[256];
    red[tid] = fmaxf(v0, v1);
    __syncthreads();
    for (int s = 128; s > 0; s >>= 1) {
        if (tid < s) red[tid] = fmaxf(red[tid], red[tid + s]);
        __syncthreads();
    }
    const float m = red[0];
    __syncthreads();

    const float e0 = expf(v0 - m);
    const float e1 = expf(v1 - m);
    red[tid] = e0 + e1;
    __syncthreads();
    for (int s = 128; s > 0; s >>= 1) {
        if (tid < s) red[tid] += red[tid + s];
        __syncthreads();
    }
    const float inv = 1.0f / red[0];
    row[tid]       = e0 * inv;
    row[tid + 256] = e1 * inv;
}

// ---------------------------------------------------------------------------
// PV: per (b,h), O[q, :] = attn[q, :] @ V  (V in [B,H,S,DK])
// Writes O directly in [B,S,D] layout (col = h*DK + dk).
// Grid: (S/64, B*H)
// ---------------------------------------------------------------------------
__global__ __launch_bounds__(256) void pv_kernel(
    const float* __restrict__ attnL, const float* __restrict__ V,
    float* __restrict__ O)
{
    const int bh = blockIdx.y;
    const int qt = blockIdx.x;
    const int b = bh >> 4, h = bh & 15;

    const float* Aab = attnL + ((size_t)b * (NL_ * H_) + h) * (size_t)(S_ * S_);
    const float* Vb  = V + (size_t)bh * S_ * DK_;

    __shared__ float sA[16][64];
    __shared__ float sV[16][64];

    const int tid = threadIdx.x;
    const int tx = tid & 15, ty = tid >> 4;
    const int lm  = tid >> 2;
    const int lk4 = (tid & 3) << 2;
    const int lkk = tid >> 4;
    const int ln4 = (tid & 15) << 2;

    float acc[4][4] = {};

    for (int k0 = 0; k0 < S_; k0 += 16) {
        const float4 a4 = *(const float4*)(Aab + (size_t)(qt * 64 + lm) * S_ + k0 + lk4);
        const float4 v4 = *(const float4*)(Vb + (size_t)(k0 + lkk) * DK_ + ln4);
        sA[lk4 + 0][lm] = a4.x; sA[lk4 + 1][lm] = a4.y; sA[lk4 + 2][lm] = a4.z; sA[lk4 + 3][lm] = a4.w;
        *(float4*)&sV[lkk][ln4] = v4;
        __syncthreads();
#pragma unroll
        for (int kk = 0; kk < 16; ++kk) {
            float a0 = sA[kk][ty * 4 + 0];
            float a1 = sA[kk][ty * 4 + 1];
            float a2 = sA[kk][ty * 4 + 2];
            float a3 = sA[kk][ty * 4 + 3];
            float b0 = sV[kk][tx * 4 + 0];
            float b1 = sV[kk][tx * 4 + 1];
            float b2 = sV[kk][tx * 4 + 2];
            float b3 = sV[kk][tx * 4 + 3];
            acc[0][0] += a0 * b0; acc[0][1] += a0 * b1; acc[0][2] += a0 * b2; acc[0][3] += a0 * b3;
            acc[1][0] += a1 * b0; acc[1][1] += a1 * b1; acc[1][2] += a1 * b2; acc[1][3] += a1 * b3;
            acc[2][0] += a2 * b0; acc[2][1] += a2 * b1; acc[2][2] += a2 * b2; acc[2][3] += a2 * b3;
            acc[3][0] += a3 * b0; acc[3][1] += a3 * b1; acc[3][2] += a3 * b2; acc[3][3] += a3 * b3;
        }
        __syncthreads();
    }

#pragma unroll
    for (int i = 0; i < 4; ++i) {
        const int qr = qt * 64 + ty * 4 + i;
#pragma unroll
        for (int j = 0; j < 4; ++j) {
            const int dk = tx * 4 + j;
            O[((size_t)b * S_ + qr) * D_ + h * DK_ + dk] = acc[i][j];
        }
    }
}

// ---------------------------------------------------------------------------
// Fused residual add + LayerNorm: xout[row] = LN(xin[row] + u[row])
// One block (256 threads) per row of D=1024 (4 elems/thread). In-place safe.
// ---------------------------------------------------------------------------
__global__ __launch_bounds__(256) void add_ln_kernel(
    const float* __restrict__ xin, const float* __restrict__ u,
    const float* __restrict__ alpha, const float* __restrict__ beta,
    float* __restrict__ xout)
{
    const int row = blockIdx.x;
    const int tid = threadIdx.x;
    const float* xr = xin + (size_t)row * D_;
    const float* ur = u   + (size_t)row * D_;

    float vals[4];
    float s = 0.0f, s2 = 0.0f;
#pragma unroll
    for (int j = 0; j < 4; ++j) {
        const float t = xr[tid + j * 256] + ur[tid + j * 256];
        vals[j] = t;
        s  += t;
        s2 += t * t;
    }

    __shared__ float r1[256];
    __shared__ float r2[256];
    r1[tid] = s; r2[tid] = s2;
    __syncthreads();
    for (int st = 128; st > 0; st >>= 1) {
        if (tid < st) { r1[tid] += r1[tid + st]; r2[tid] += r2[tid + st]; }
        __syncthreads();
    }
    const float mean = r1[0] * (1.0f / 1024.0f);
    const float var  = r2[0] * (1.0f / 1024.0f) - mean * mean;
    const float inv  = rsqrtf(var + EPS_);

    float* xo = xout + (size_t)row * D_;
#pragma unroll
    for (int j = 0; j < 4; ++j) {
        const int c = tid + j * 256;
        xo[c] = alpha[c] * ((vals[j] - mean) * inv) + beta[c];
    }
}

// ---------------------------------------------------------------------------
// Launcher
// ---------------------------------------------------------------------------
extern "C" void kernel_launch(void* const* d_in, const int* in_sizes, int n_in,
                              void* d_out, int out_size, void* d_ws, size_t ws_size,
                              hipStream_t stream)
{
    const float* src = (const float*)d_in[0];
    const float* Wq  = (const float*)d_in[1];
    const float* bq  = (const float*)d_in[2];
    const float* Wk  = (const float*)d_in[3];
    const float* bk  = (const float*)d_in[4];
    const float* Wv  = (const float*)d_in[5];
    const float* bv  = (const float*)d_in[6];
    const float* Wo  = (const float*)d_in[7];
    const float* bo  = (const float*)d_in[8];
    const float* l1a = (const float*)d_in[9];
    const float* l1b = (const float*)d_in[10];
    const float* l2a = (const float*)d_in[11];
    const float* l2b = (const float*)d_in[12];
    const float* W1  = (const float*)d_in[13];
    const float* b1  = (const float*)d_in[14];
    const float* W2  = (const float*)d_in[15];
    const float* b2  = (const float*)d_in[16];

    float* outX    = (float*)d_out;
    float* outAttn = outX + (size_t)M_ * D_;

    // Workspace layout (floats): x | q | k | v | ff   (~75.5 MB total)
    float* ws = (float*)d_ws;
    float* x  = ws;
    float* qb = x  + (size_t)M_ * D_;
    float* kb = qb + (size_t)M_ * D_;
    float* vb = kb + (size_t)M_ * D_;
    float* ffb = vb + (size_t)M_ * D_;  // M_*DFF_

    hipMemcpyAsync(x, src, sizeof(float) * (size_t)M_ * D_,
                   hipMemcpyDeviceToDevice, stream);

    const dim3 blk(256);
    const dim3 gProj(D_ / 64, M_ / 64);     // 16 x 64
    const dim3 gFF1(DFF_ / 64, M_ / 64);    // 8 x 64
    const dim3 gQKT(S_ / 64, S_ / 64, B_ * H_);
    const dim3 gPV(S_ / 64, B_ * H_);

    for (int i = 0; i < NL_; ++i) {
        const float* Wqi = Wq + (size_t)i * D_ * D_;
        const float* Wki = Wk + (size_t)i * D_ * D_;
        const float* Wvi = Wv + (size_t)i * D_ * D_;
        const float* Woi = Wo + (size_t)i * D_ * D_;
        const float* W1i = W1 + (size_t)i * D_ * DFF_;
        const float* W2i = W2 + (size_t)i * DFF_ * D_;
        float* attnL = outAttn + (size_t)i * H_ * S_ * S_;

        // QKV projections with fused reshape to [B,H,S,DK]
        gemm64<1><<<gProj, blk, 0, stream>>>(x, Wqi, bq + i * D_, qb, M_, D_, D_);
        gemm64<1><<<gProj, blk, 0, stream>>>(x, Wki, bk + i * D_, kb, M_, D_, D_);
        gemm64<1><<<gProj, blk, 0, stream>>>(x, Wvi, bv + i * D_, vb, M_, D_, D_);

        // scores -> d_out attn slice, softmax in place, then PV
        qkt_kernel<<<gQKT, blk, 0, stream>>>(qb, kb, attnL);
        softmax_kernel<<<dim3(B_ * H_ * S_), blk, 0, stream>>>(attnL);
        pv_kernel<<<gPV, blk, 0, stream>>>(attnL, vb, kb);  // kb now holds O in [B,S,D]

        // output projection (into qb), then residual + LN1 (in-place x)
        gemm64<0><<<gProj, blk, 0, stream>>>(kb, Woi, bo + i * D_, qb, M_, D_, D_);
        add_ln_kernel<<<dim3(M_), blk, 0, stream>>>(x, qb, l1a + i * D_, l1b + i * D_, x);

        // FFN: relu(x@W1+b1) @ W2 + b2, then residual + LN2
        gemm64<2><<<gFF1, blk, 0, stream>>>(x, W1i, b1 + i * DFF_, ffb, M_, DFF_, D_);
        gemm64<0><<<gProj, blk, 0, stream>>>(ffb, W2i, b2 + i * D_, qb, M_, D_, DFF_);
        add_ln_kernel<<<dim3(M_), blk, 0, stream>>>(x, qb, l2a + i * D_, l2b + i * D_, x);
    }

    hipMemcpyAsync(outX, x, sizeof(float) * (size_t)M_ * D_,
                   hipMemcpyDeviceToDevice, stream);
}